// Round 10
// baseline (347.235 us; speedup 1.0000x reference)
//
#include <hip/hip_runtime.h>
#include <hip/hip_fp16.h>
#include <math.h>

#define N_NODES 50000
#define N_EDGES 600000
#define N_PATHS 3
#define DIM 128
#define NROWS_ALL (N_PATHS * N_NODES)      // 150000
#define NE_ALL (N_PATHS * N_EDGES)         // 1800000
#define SCAN_BLOCKS ((NROWS_ALL + 1023) / 1024)   // 147
#define NTILES_ALL (NROWS_ALL / 16)        // 9375
#define NTILES_N (N_NODES / 16)            // 3125

// CSR-build partitioning: LDS histograms, zero global atomics
#define HB_CHUNKS 24
#define CHUNK_E (N_EDGES / HB_CHUNKS)      // 25000
// hist: u16-packed bins, 2 ranges
#define H2_BINS 32768
#define H2_RANGES 2
// fill: u32 cursors, 4 ranges
#define HF_BINS 16384
#define HF_RANGES 4

typedef __attribute__((ext_vector_type(8))) short bf16x8;
typedef __attribute__((ext_vector_type(4))) float f32x4;

__device__ __forceinline__ unsigned short f2bf(float f) {
    unsigned u = __float_as_uint(f);
    u += 0x7FFF + ((u >> 16) & 1);          // RNE
    return (unsigned short)(u >> 16);
}
__device__ __forceinline__ float tanh_fast(float x) {
    return 1.0f - 2.0f / (__expf(2.0f * x) + 1.0f);
}

// ---------------- convert h -> bf16 ----------------
__global__ void conv_h(const float* __restrict__ h, unsigned int* __restrict__ hb) {
    int i = blockIdx.x * blockDim.x + threadIdx.x;
    if (i >= N_NODES * DIM / 8) return;
    const float4* h4 = (const float4*)h;
    float4 a = h4[2 * i], b = h4[2 * i + 1];
    uint4 o;
    o.x = f2bf(a.x) | ((unsigned)f2bf(a.y) << 16);
    o.y = f2bf(a.z) | ((unsigned)f2bf(a.w) << 16);
    o.z = f2bf(b.x) | ((unsigned)f2bf(b.y) << 16);
    o.w = f2bf(b.z) | ((unsigned)f2bf(b.w) << 16);
    ((uint4*)hb)[i] = o;
}

// ---------------- weights -> bf16 in MFMA fragment-major layout ----------------
__global__ void conv_w(const float* __restrict__ W_gc, const float* __restrict__ w1,
                       uint4* __restrict__ wsw) {
    int i = blockIdx.x * blockDim.x + threadIdx.x;
    if (i >= (N_PATHS + 1) * 2048) return;
    int mat = i >> 11;
    int rem = i & 2047;
    int frag = rem >> 6, lane = rem & 63;
    int n0 = frag >> 2, q = frag & 3;
    int quad = lane >> 4, m = lane & 15;
    int n = n0 * 16 + m;
    int kbase = q * 32 + quad * 8;
    const float* src = (mat < N_PATHS) ? (W_gc + (size_t)mat * DIM * DIM) : w1;
    unsigned short t[8];
#pragma unroll
    for (int j = 0; j < 8; ++j) t[j] = f2bf(src[(size_t)(kbase + j) * DIM + n]);
    uint4 o;
    o.x = t[0] | ((unsigned)t[1] << 16);
    o.y = t[2] | ((unsigned)t[3] << 16);
    o.z = t[4] | ((unsigned)t[5] << 16);
    o.w = t[6] | ((unsigned)t[7] << 16);
    wsw[i] = o;
}

// ---------------- hist: u16-packed LDS histogram (2 bins per u32), 2 ranges ----------------
__global__ __launch_bounds__(256) void hist_kernel(const int* __restrict__ esrc,
                                                   const int* __restrict__ edst,
                                                   int* __restrict__ pcnt_out,
                                                   int* __restrict__ pcnt_in) {
    __shared__ unsigned bins32[H2_BINS / 2];   // 16384 u32 = 64 KB
    int tid = threadIdx.x;
    {   uint4* b4 = (uint4*)bins32;
        for (int i = tid; i < H2_BINS / 8; i += 256) b4[i] = make_uint4(0, 0, 0, 0);
    }
    int b = blockIdx.x;
    int c = b % HB_CHUNKS;
    int r = (b / HB_CHUNKS) % H2_RANGES;
    int p = (b / (HB_CHUNKS * H2_RANGES)) % N_PATHS;
    int type = b / (HB_CHUNKS * H2_RANGES * N_PATHS);
    const int* ptr = (type == 0 ? esrc : edst) + (size_t)p * N_EDGES + c * CHUNK_E;
    int r0 = r * H2_BINS;
    __syncthreads();
    const int4* p4 = (const int4*)ptr;
    // CHUNK_E/4 = 6250; even i always has valid i+1
    for (int i = tid * 2; i < CHUNK_E / 4; i += 512) {
        int4 a = p4[i];
        int4 bb = p4[i + 1];
        int l;
        l = a.x - r0;  if ((unsigned)l < H2_BINS) atomicAdd(&bins32[l >> 1], 1u << ((l & 1) << 4));
        l = a.y - r0;  if ((unsigned)l < H2_BINS) atomicAdd(&bins32[l >> 1], 1u << ((l & 1) << 4));
        l = a.z - r0;  if ((unsigned)l < H2_BINS) atomicAdd(&bins32[l >> 1], 1u << ((l & 1) << 4));
        l = a.w - r0;  if ((unsigned)l < H2_BINS) atomicAdd(&bins32[l >> 1], 1u << ((l & 1) << 4));
        l = bb.x - r0; if ((unsigned)l < H2_BINS) atomicAdd(&bins32[l >> 1], 1u << ((l & 1) << 4));
        l = bb.y - r0; if ((unsigned)l < H2_BINS) atomicAdd(&bins32[l >> 1], 1u << ((l & 1) << 4));
        l = bb.z - r0; if ((unsigned)l < H2_BINS) atomicAdd(&bins32[l >> 1], 1u << ((l & 1) << 4));
        l = bb.w - r0; if ((unsigned)l < H2_BINS) atomicAdd(&bins32[l >> 1], 1u << ((l & 1) << 4));
    }
    __syncthreads();
    int bound = min(H2_BINS, N_NODES - r0);    // 32768 or 17232 (both even)
    int* dst = (type == 0 ? pcnt_out : pcnt_in) + (size_t)c * NROWS_ALL + p * N_NODES + r0;
    for (int j = tid; j < bound / 2; j += 256) {
        unsigned u = bins32[j];
        int2 w = make_int2((int)(u & 0xFFFFu), (int)(u >> 16));
        *(int2*)(dst + 2 * j) = w;
    }
}

// ---------------- scan pass1 (fused merge): chunk-private sums -> cnt/sc_out, block sums ----------------
__global__ __launch_bounds__(256) void scan_pass1(const int* __restrict__ pcnt_out,
                                                  const int* __restrict__ pcnt_in,
                                                  int* __restrict__ cnt_out,
                                                  int* __restrict__ cnt_in,
                                                  float* __restrict__ sc_out,
                                                  int* __restrict__ partial) {
    __shared__ int lds[256];
    int t = threadIdx.x;
    int base = blockIdx.x * 1024 + t * 4;
    int4 ci = make_int4(0, 0, 0, 0);
    if (base < NROWS_ALL) {
        int4 co = make_int4(0, 0, 0, 0);
#pragma unroll
        for (int c = 0; c < HB_CHUNKS; ++c) {
            int4 vi = *(const int4*)(pcnt_in + (size_t)c * NROWS_ALL + base);
            int4 vo = *(const int4*)(pcnt_out + (size_t)c * NROWS_ALL + base);
            ci.x += vi.x; ci.y += vi.y; ci.z += vi.z; ci.w += vi.w;
            co.x += vo.x; co.y += vo.y; co.z += vo.z; co.w += vo.w;
        }
        *(int4*)(cnt_in + base) = ci;
        *(int4*)(cnt_out + base) = co;
        float4 sc;
        sc.x = rsqrtf(fmaxf((float)co.x, 1.0f));
        sc.y = rsqrtf(fmaxf((float)co.y, 1.0f));
        sc.z = rsqrtf(fmaxf((float)co.z, 1.0f));
        sc.w = rsqrtf(fmaxf((float)co.w, 1.0f));
        *(float4*)(sc_out + base) = sc;
    }
    int s = ci.x + ci.y + ci.z + ci.w;
    lds[t] = s; __syncthreads();
    for (int off = 1; off < 256; off <<= 1) {
        int u = (t >= off) ? lds[t - off] : 0;
        __syncthreads();
        lds[t] += u;
        __syncthreads();
    }
    if (t == 255) partial[blockIdx.x] = lds[255];
}

__global__ __launch_bounds__(256) void scan_pass2(int* __restrict__ partial) {
    __shared__ int lds[256];
    int t = threadIdx.x;
    int s = (t < SCAN_BLOCKS) ? partial[t] : 0;
    lds[t] = s; __syncthreads();
    for (int off = 1; off < 256; off <<= 1) {
        int u = (t >= off) ? lds[t - off] : 0;
        __syncthreads();
        lds[t] += u;
        __syncthreads();
    }
    if (t < SCAN_BLOCKS) partial[t] = lds[t] - s;
}

// ---------------- scan pass3 (fused chunkbase): cursor + per-chunk write bases ----------------
__global__ __launch_bounds__(256) void scan_pass3(const int* __restrict__ cnt,
                                                  const int* __restrict__ partial,
                                                  int* __restrict__ cursor,
                                                  int* __restrict__ pcnt_in) {
    __shared__ int lds[256];
    int t = threadIdx.x;
    int base = blockIdx.x * 1024 + t * 4;
    int4 v = make_int4(0, 0, 0, 0);
    if (base < NROWS_ALL) v = *(const int4*)(cnt + base);
    int s = v.x + v.y + v.z + v.w;
    lds[t] = s; __syncthreads();
    for (int off = 1; off < 256; off <<= 1) {
        int u = (t >= off) ? lds[t - off] : 0;
        __syncthreads();
        lds[t] += u;
        __syncthreads();
    }
    if (base < NROWS_ALL) {
        int run = partial[blockIdx.x] + lds[t] - s;
        int vv[4] = {v.x, v.y, v.z, v.w};
        int rb[4];
#pragma unroll
        for (int j = 0; j < 4; ++j) { cursor[base + j] = run; rb[j] = run; run += vv[j]; }
#pragma unroll
        for (int c = 0; c < HB_CHUNKS; ++c) {
            int4 pc = *(const int4*)(pcnt_in + (size_t)c * NROWS_ALL + base);
            *(int4*)(pcnt_in + (size_t)c * NROWS_ALL + base) = make_int4(rb[0], rb[1], rb[2], rb[3]);
            rb[0] += pc.x; rb[1] += pc.y; rb[2] += pc.z; rb[3] += pc.w;
        }
    }
}

// ---------------- fill2: place (src | f16(sc)<<16) via LDS cursors ----------------
__global__ __launch_bounds__(256) void fill2_kernel(const int* __restrict__ esrc,
                                                    const int* __restrict__ edst,
                                                    const int* __restrict__ pcnt_in,
                                                    const float* __restrict__ sc_out,
                                                    unsigned int* __restrict__ colsc) {
    __shared__ int curs[HF_BINS];
    int tid = threadIdx.x;
    int b = blockIdx.x;
    int c = b % HB_CHUNKS;
    int r = (b / HB_CHUNKS) % HF_RANGES;
    int p = b / (HB_CHUNKS * HF_RANGES);
    int r0 = r * HF_BINS;
    int bound = min(HF_BINS, N_NODES - r0);
    const int* basep = pcnt_in + (size_t)c * NROWS_ALL + p * N_NODES + r0;
    for (int i = tid; i < bound; i += 256) curs[i] = basep[i];
    __syncthreads();
    const float* scp = sc_out + p * N_NODES;
    const int4* sp4 = (const int4*)(esrc + (size_t)p * N_EDGES + c * CHUNK_E);
    const int4* dp4 = (const int4*)(edst + (size_t)p * N_EDGES + c * CHUNK_E);
    for (int i = tid * 2; i < CHUNK_E / 4; i += 512) {
        int4 dv0 = dp4[i];
        int4 dv1 = dp4[i + 1];
        int4 sv0 = sp4[i];
        int4 sv1 = sp4[i + 1];
        int l;
        l = dv0.x - r0; if ((unsigned)l < HF_BINS) { int pos = atomicAdd(&curs[l], 1); colsc[pos] = (unsigned)sv0.x | ((unsigned)__half_as_ushort(__float2half(scp[sv0.x])) << 16); }
        l = dv0.y - r0; if ((unsigned)l < HF_BINS) { int pos = atomicAdd(&curs[l], 1); colsc[pos] = (unsigned)sv0.y | ((unsigned)__half_as_ushort(__float2half(scp[sv0.y])) << 16); }
        l = dv0.z - r0; if ((unsigned)l < HF_BINS) { int pos = atomicAdd(&curs[l], 1); colsc[pos] = (unsigned)sv0.z | ((unsigned)__half_as_ushort(__float2half(scp[sv0.z])) << 16); }
        l = dv0.w - r0; if ((unsigned)l < HF_BINS) { int pos = atomicAdd(&curs[l], 1); colsc[pos] = (unsigned)sv0.w | ((unsigned)__half_as_ushort(__float2half(scp[sv0.w])) << 16); }
        l = dv1.x - r0; if ((unsigned)l < HF_BINS) { int pos = atomicAdd(&curs[l], 1); colsc[pos] = (unsigned)sv1.x | ((unsigned)__half_as_ushort(__float2half(scp[sv1.x])) << 16); }
        l = dv1.y - r0; if ((unsigned)l < HF_BINS) { int pos = atomicAdd(&curs[l], 1); colsc[pos] = (unsigned)sv1.y | ((unsigned)__half_as_ushort(__float2half(scp[sv1.y])) << 16); }
        l = dv1.z - r0; if ((unsigned)l < HF_BINS) { int pos = atomicAdd(&curs[l], 1); colsc[pos] = (unsigned)sv1.z | ((unsigned)__half_as_ushort(__float2half(scp[sv1.z])) << 16); }
        l = dv1.w - r0; if ((unsigned)l < HF_BINS) { int pos = atomicAdd(&curs[l], 1); colsc[pos] = (unsigned)sv1.w | ((unsigned)__half_as_ushort(__float2half(scp[sv1.w])) << 16); }
    }
}

// ---------------- gather: 8 edge-slots x 8 lanes x 8 dims; 2 waves (dim-halves) per node ----------------
__global__ __launch_bounds__(256) void gather_kernel(const int* __restrict__ cursor,
                                                     const int* __restrict__ cnt_in,
                                                     const unsigned int* __restrict__ colsc,
                                                     const uint4* __restrict__ hb4,
                                                     uint4* __restrict__ aggb4) {
    int wave = threadIdx.x >> 6, lane = threadIdx.x & 63;
    int wid = blockIdx.x * 2 + (wave >> 1);
    int dh = wave & 1;             // dim half 0/1
    int ss = lane >> 3;            // edge slot 0..7
    int ln = lane & 7;             // dim group within half
    if (wid >= NROWS_ALL) return;
    int beg = cursor[wid];
    int end = beg + cnt_in[wid];
    int idx = dh * 8 + ln;         // uint4 index within 256B row
    float acc[8] = {};
    for (int e = beg + ss; e < end; e += 8) {
        unsigned cs = colsc[e];                          // broadcast within slot
        int s = cs & 0xFFFF;
        float sc = __half2float(__ushort_as_half((unsigned short)(cs >> 16)));
        uint4 v = hb4[s * 16 + idx];
        acc[0] = fmaf(__uint_as_float(v.x << 16),        sc, acc[0]);
        acc[1] = fmaf(__uint_as_float(v.x & 0xFFFF0000u), sc, acc[1]);
        acc[2] = fmaf(__uint_as_float(v.y << 16),        sc, acc[2]);
        acc[3] = fmaf(__uint_as_float(v.y & 0xFFFF0000u), sc, acc[3]);
        acc[4] = fmaf(__uint_as_float(v.z << 16),        sc, acc[4]);
        acc[5] = fmaf(__uint_as_float(v.z & 0xFFFF0000u), sc, acc[5]);
        acc[6] = fmaf(__uint_as_float(v.w << 16),        sc, acc[6]);
        acc[7] = fmaf(__uint_as_float(v.w & 0xFFFF0000u), sc, acc[7]);
    }
    // reduce across the 8 slots
#pragma unroll
    for (int j = 0; j < 8; ++j) {
        acc[j] += __shfl_xor(acc[j], 8, 64);
        acc[j] += __shfl_xor(acc[j], 16, 64);
        acc[j] += __shfl_xor(acc[j], 32, 64);
    }
    if (ss == 0) {
        uint4 o;
        o.x = f2bf(acc[0]) | ((unsigned)f2bf(acc[1]) << 16);
        o.y = f2bf(acc[2]) | ((unsigned)f2bf(acc[3]) << 16);
        o.z = f2bf(acc[4]) | ((unsigned)f2bf(acc[5]) << 16);
        o.w = f2bf(acc[6]) | ((unsigned)f2bf(acc[7]) << 16);
        int t = wid >> 4, m = wid & 15;
        aggb4[(size_t)t * 256 + idx * 16 + m] = o;   // q*64+qd*16 == idx*16
    }
}

// ---------------- score pass: gemm1 -> LDS transpose -> gemm2 -> tanh -> score ----------------
__global__ __launch_bounds__(256, 4) void score_pass(const uint4* __restrict__ aggb4,
                                                     const uint4* __restrict__ wsw,
                                                     const int* __restrict__ cnt_in,
                                                     const float* __restrict__ b_gc,
                                                     const float* __restrict__ b1,
                                                     const float* __restrict__ w2,
                                                     float* __restrict__ scorep) {
    __shared__ float zS[4][16][132];
    int wave = threadIdx.x >> 6, lane = threadIdx.x & 63;
    int m = lane & 15, quad = lane >> 4;
    int t = blockIdx.x * 4 + wave;
    if (t >= NTILES_ALL) return;
    int r0 = t * 16;
    int p = r0 / N_NODES;
    const uint4* At = aggb4 + (size_t)t * 256 + lane;
    bf16x8 a[4];
#pragma unroll
    for (int q = 0; q < 4; ++q) a[q] = *(const bf16x8*)&At[q * 64];
    float s[4];
#pragma unroll
    for (int rg = 0; rg < 4; ++rg)
        s[rg] = rsqrtf(fmaxf((float)cnt_in[r0 + quad * 4 + rg], 1.0f));
    const uint4* Bp = wsw + (size_t)p * 2048 + lane;
    const float* bgc = b_gc + p * DIM;
    float (*zw)[132] = zS[wave];
#pragma unroll
    for (int n0 = 0; n0 < 8; ++n0) {
        f32x4 acc = {0.f, 0.f, 0.f, 0.f};
#pragma unroll
        for (int q = 0; q < 4; ++q) {
            bf16x8 b = *(const bf16x8*)&Bp[(n0 * 4 + q) * 64];
            acc = __builtin_amdgcn_mfma_f32_16x16x32_bf16(a[q], b, acc, 0, 0, 0);
        }
        int colj = n0 * 16 + m;
        float bias = bgc[colj];
#pragma unroll
        for (int rg = 0; rg < 4; ++rg)
            zw[quad * 4 + rg][colj] = acc[rg] * s[rg] + bias;
    }
    bf16x8 sa[4];
#pragma unroll
    for (int q = 0; q < 4; ++q) {
        const float* pr = &zw[m][q * 32 + quad * 8];
        float4 f0 = *(const float4*)pr;
        float4 f1 = *(const float4*)(pr + 4);
        bf16x8 tt;
        tt[0] = f2bf(f0.x); tt[1] = f2bf(f0.y); tt[2] = f2bf(f0.z); tt[3] = f2bf(f0.w);
        tt[4] = f2bf(f1.x); tt[5] = f2bf(f1.y); tt[6] = f2bf(f1.z); tt[7] = f2bf(f1.w);
        sa[q] = tt;
    }
    const uint4* W1 = wsw + (size_t)N_PATHS * 2048 + lane;
    float rsum[4] = {0.f, 0.f, 0.f, 0.f};
#pragma unroll
    for (int n0 = 0; n0 < 8; ++n0) {
        f32x4 acc = {0.f, 0.f, 0.f, 0.f};
#pragma unroll
        for (int q = 0; q < 4; ++q) {
            bf16x8 b = *(const bf16x8*)&W1[(n0 * 4 + q) * 64];
            acc = __builtin_amdgcn_mfma_f32_16x16x32_bf16(sa[q], b, acc, 0, 0, 0);
        }
        int colj = n0 * 16 + m;
        float bj = b1[colj], wj = w2[colj];
#pragma unroll
        for (int rg = 0; rg < 4; ++rg)
            rsum[rg] += tanh_fast(acc[rg] + bj) * wj;
    }
#pragma unroll
    for (int off = 1; off < 64; off <<= 1)
#pragma unroll
        for (int rg = 0; rg < 4; ++rg) rsum[rg] += __shfl_xor(rsum[rg], off, 64);
    if (lane == 0)
        scorep[t] = rsum[0] + rsum[1] + rsum[2] + rsum[3];
}

// ---------------- beta = softmax( path-bucketed mean of scorep ) ----------------
__global__ __launch_bounds__(1024) void beta_kernel(const float* __restrict__ scorep,
                                                    float* __restrict__ beta) {
    __shared__ float red[3][1024];
    int t = threadIdx.x;
    float a0 = 0.f, a1 = 0.f, a2 = 0.f;
    for (int i = t; i < NTILES_ALL; i += 1024) {
        float v = scorep[i];
        int p = (i * 16) / N_NODES;
        if (p == 0) a0 += v; else if (p == 1) a1 += v; else a2 += v;
    }
    red[0][t] = a0; red[1][t] = a1; red[2][t] = a2;
    __syncthreads();
    for (int off = 512; off > 0; off >>= 1) {
        if (t < off) {
            red[0][t] += red[0][t + off];
            red[1][t] += red[1][t + off];
            red[2][t] += red[2][t + off];
        }
        __syncthreads();
    }
    if (t == 0) {
        float a = red[0][0] / (float)N_NODES;
        float b = red[1][0] / (float)N_NODES;
        float c = red[2][0] / (float)N_NODES;
        float mx = fmaxf(a, fmaxf(b, c));
        float e0 = expf(a - mx), e1 = expf(b - mx), e2 = expf(c - mx);
        float sm = e0 + e1 + e2;
        beta[0] = e0 / sm; beta[1] = e1 / sm; beta[2] = e2 / sm;
    }
}

// ---------------- out pass: out = sum_p beta_p * ((agg_p @ W_p)*s + b_p) ----------------
__global__ __launch_bounds__(256, 4) void out_pass(const uint4* __restrict__ aggb4,
                                                   const uint4* __restrict__ wsw,
                                                   const int* __restrict__ cnt_in,
                                                   const float* __restrict__ b_gc,
                                                   const float* __restrict__ beta,
                                                   float* __restrict__ out) {
    __shared__ float zS[4][16][132];
    int wave = threadIdx.x >> 6, lane = threadIdx.x & 63;
    int m = lane & 15, quad = lane >> 4;
    int t = blockIdx.x * 4 + wave;
    if (t >= NTILES_N) return;
    int r0 = t * 16;
    float of[8][4] = {};
#pragma unroll
    for (int p = 0; p < N_PATHS; ++p) {
        const uint4* At = aggb4 + (size_t)(p * NTILES_N + t) * 256 + lane;
        bf16x8 a[4];
#pragma unroll
        for (int q = 0; q < 4; ++q) a[q] = *(const bf16x8*)&At[q * 64];
        float s[4];
#pragma unroll
        for (int rg = 0; rg < 4; ++rg)
            s[rg] = rsqrtf(fmaxf((float)cnt_in[p * N_NODES + r0 + quad * 4 + rg], 1.0f));
        float bp = beta[p];
        const uint4* Bp = wsw + (size_t)p * 2048 + lane;
        const float* bgc = b_gc + p * DIM;
#pragma unroll
        for (int n0 = 0; n0 < 8; ++n0) {
            f32x4 acc = {0.f, 0.f, 0.f, 0.f};
#pragma unroll
            for (int q = 0; q < 4; ++q) {
                bf16x8 b = *(const bf16x8*)&Bp[(n0 * 4 + q) * 64];
                acc = __builtin_amdgcn_mfma_f32_16x16x32_bf16(a[q], b, acc, 0, 0, 0);
            }
            float bias = bgc[n0 * 16 + m];
#pragma unroll
            for (int rg = 0; rg < 4; ++rg)
                of[n0][rg] = fmaf(bp, acc[rg] * s[rg] + bias, of[n0][rg]);
        }
    }
    float (*zw)[132] = zS[wave];
#pragma unroll
    for (int n0 = 0; n0 < 8; ++n0)
#pragma unroll
        for (int rg = 0; rg < 4; ++rg)
            zw[quad * 4 + rg][n0 * 16 + m] = of[n0][rg];
#pragma unroll
    for (int i = 0; i < 8; ++i) {
        int fi = i * 64 + lane;
        int row = fi >> 5, c4 = fi & 31;
        float4 v = *(const float4*)&zw[row][c4 * 4];
        *(float4*)(out + (size_t)(r0 + row) * DIM + c4 * 4) = v;
    }
}

extern "C" void kernel_launch(void* const* d_in, const int* in_sizes, int n_in,
                              void* d_out, int out_size, void* d_ws, size_t ws_size,
                              hipStream_t stream) {
    const float* h    = (const float*)d_in[0];
    const float* W_gc = (const float*)d_in[1];
    const float* b_gc = (const float*)d_in[2];
    const float* w1   = (const float*)d_in[3];
    const float* b1   = (const float*)d_in[4];
    const float* w2   = (const float*)d_in[5];
    const int* esrc   = (const int*)d_in[6];
    const int* edst   = (const int*)d_in[7];
    float* out        = (float*)d_out;

    // workspace layout (4-byte word offsets); total 26.04M words < proven 29.28M capacity
    int*   cnt_out = (int*)d_ws;                                // 150000
    int*   cnt_in  = cnt_out + NROWS_ALL;                       // 150000
    float* beta    = (float*)d_ws + 300004;                     // 4 (+pad)
    int*   partial = (int*)d_ws + 300032;                       // 256
    float* sc_out  = (float*)d_ws + 300288;                     // 150000 (reused as scorep)
    float* scorep  = (float*)d_ws + 300288;                     //   after gather completes
    uint4* wsw     = (uint4*)((int*)d_ws + 450288);             // 32768 words
    unsigned int* aggb = (unsigned int*)((int*)d_ws + 483056);  // 9.6M words
    int*   cursor  = (int*)d_ws + 10233056;                     // 150000
    unsigned int* colsc = (unsigned int*)((int*)d_ws + 10383056);    // 1.8M words
    unsigned int* hb    = (unsigned int*)((int*)d_ws + 12183056);    // 3.2M words
    int*   pcnt_out = (int*)d_ws + 15383056;                    // 3.6M words
    int*   pcnt_in  = (int*)d_ws + 18983056;                    // 3.6M words (ends 22.58M)

    conv_h<<<(N_NODES * DIM / 8 + 255) / 256, 256, 0, stream>>>(h, hb);
    conv_w<<<((N_PATHS + 1) * 2048 + 255) / 256, 256, 0, stream>>>(W_gc, w1, wsw);

    hist_kernel<<<2 * N_PATHS * H2_RANGES * HB_CHUNKS, 256, 0, stream>>>(
        esrc, edst, pcnt_out, pcnt_in);

    scan_pass1<<<SCAN_BLOCKS, 256, 0, stream>>>(
        pcnt_out, pcnt_in, cnt_out, cnt_in, sc_out, partial);
    scan_pass2<<<1, 256, 0, stream>>>(partial);
    scan_pass3<<<SCAN_BLOCKS, 256, 0, stream>>>(cnt_in, partial, cursor, pcnt_in);

    fill2_kernel<<<N_PATHS * HF_RANGES * HB_CHUNKS, 256, 0, stream>>>(
        esrc, edst, pcnt_in, sc_out, colsc);

    gather_kernel<<<(NROWS_ALL + 1) / 2, 256, 0, stream>>>(
        cursor, cnt_in, colsc, (const uint4*)hb, (uint4*)aggb);

    score_pass<<<(NTILES_ALL + 3) / 4, 256, 0, stream>>>(
        (const uint4*)aggb, wsw, cnt_in, b_gc, b1, w2, scorep);

    beta_kernel<<<1, 1024, 0, stream>>>(scorep, beta);

    out_pass<<<(NTILES_N + 3) / 4, 256, 0, stream>>>(
        (const uint4*)aggb, wsw, cnt_in, b_gc, beta, out);
}

// Round 11
// 305.120 us; speedup vs baseline: 1.1380x; 1.1380x over previous
//
#include <hip/hip_runtime.h>
#include <hip/hip_fp16.h>
#include <math.h>

#define N_NODES 50000
#define N_EDGES 600000
#define N_PATHS 3
#define DIM 128
#define NROWS_ALL (N_PATHS * N_NODES)      // 150000
#define NE_ALL (N_PATHS * N_EDGES)         // 1800000
#define SCAN_BLOCKS ((NROWS_ALL + 1023) / 1024)   // 147
#define NTILES_ALL (NROWS_ALL / 16)        // 9375
#define NTILES_N (N_NODES / 16)            // 3125

// CSR-build partitioning: LDS histograms, zero global atomics
#define HB_CHUNKS 24
#define CHUNK_E (N_EDGES / HB_CHUNKS)      // 25000
// hist: u16-packed bins, 2 ranges
#define H2_BINS 32768
#define H2_RANGES 2
// fill: u32 cursors, 4 ranges
#define HF_BINS 16384
#define HF_RANGES 4

typedef __attribute__((ext_vector_type(8))) short bf16x8;
typedef __attribute__((ext_vector_type(4))) float f32x4;

__device__ __forceinline__ unsigned short f2bf(float f) {
    unsigned u = __float_as_uint(f);
    u += 0x7FFF + ((u >> 16) & 1);          // RNE
    return (unsigned short)(u >> 16);
}
__device__ __forceinline__ float tanh_fast(float x) {
    return 1.0f - 2.0f / (__expf(2.0f * x) + 1.0f);
}

// ---------------- convert h -> bf16 ----------------
__global__ void conv_h(const float* __restrict__ h, unsigned int* __restrict__ hb) {
    int i = blockIdx.x * blockDim.x + threadIdx.x;
    if (i >= N_NODES * DIM / 8) return;
    const float4* h4 = (const float4*)h;
    float4 a = h4[2 * i], b = h4[2 * i + 1];
    uint4 o;
    o.x = f2bf(a.x) | ((unsigned)f2bf(a.y) << 16);
    o.y = f2bf(a.z) | ((unsigned)f2bf(a.w) << 16);
    o.z = f2bf(b.x) | ((unsigned)f2bf(b.y) << 16);
    o.w = f2bf(b.z) | ((unsigned)f2bf(b.w) << 16);
    ((uint4*)hb)[i] = o;
}

// ---------------- weights -> bf16 in MFMA fragment-major layout ----------------
__global__ void conv_w(const float* __restrict__ W_gc, const float* __restrict__ w1,
                       uint4* __restrict__ wsw) {
    int i = blockIdx.x * blockDim.x + threadIdx.x;
    if (i >= (N_PATHS + 1) * 2048) return;
    int mat = i >> 11;
    int rem = i & 2047;
    int frag = rem >> 6, lane = rem & 63;
    int n0 = frag >> 2, q = frag & 3;
    int quad = lane >> 4, m = lane & 15;
    int n = n0 * 16 + m;
    int kbase = q * 32 + quad * 8;
    const float* src = (mat < N_PATHS) ? (W_gc + (size_t)mat * DIM * DIM) : w1;
    unsigned short t[8];
#pragma unroll
    for (int j = 0; j < 8; ++j) t[j] = f2bf(src[(size_t)(kbase + j) * DIM + n]);
    uint4 o;
    o.x = t[0] | ((unsigned)t[1] << 16);
    o.y = t[2] | ((unsigned)t[3] << 16);
    o.z = t[4] | ((unsigned)t[5] << 16);
    o.w = t[6] | ((unsigned)t[7] << 16);
    wsw[i] = o;
}

// ---------------- hist: u16-packed LDS histogram (2 bins per u32), 2 ranges ----------------
__global__ __launch_bounds__(256) void hist_kernel(const int* __restrict__ esrc,
                                                   const int* __restrict__ edst,
                                                   int* __restrict__ pcnt_out,
                                                   int* __restrict__ pcnt_in) {
    __shared__ unsigned bins32[H2_BINS / 2];   // 16384 u32 = 64 KB
    int tid = threadIdx.x;
    {   uint4* b4 = (uint4*)bins32;
        for (int i = tid; i < H2_BINS / 8; i += 256) b4[i] = make_uint4(0, 0, 0, 0);
    }
    int b = blockIdx.x;
    int c = b % HB_CHUNKS;
    int r = (b / HB_CHUNKS) % H2_RANGES;
    int p = (b / (HB_CHUNKS * H2_RANGES)) % N_PATHS;
    int type = b / (HB_CHUNKS * H2_RANGES * N_PATHS);
    const int* ptr = (type == 0 ? esrc : edst) + (size_t)p * N_EDGES + c * CHUNK_E;
    int r0 = r * H2_BINS;
    __syncthreads();
    const int4* p4 = (const int4*)ptr;
    for (int i = tid * 2; i < CHUNK_E / 4; i += 512) {
        int4 a = p4[i];
        int4 bb = p4[i + 1];
        int l;
        l = a.x - r0;  if ((unsigned)l < H2_BINS) atomicAdd(&bins32[l >> 1], 1u << ((l & 1) << 4));
        l = a.y - r0;  if ((unsigned)l < H2_BINS) atomicAdd(&bins32[l >> 1], 1u << ((l & 1) << 4));
        l = a.z - r0;  if ((unsigned)l < H2_BINS) atomicAdd(&bins32[l >> 1], 1u << ((l & 1) << 4));
        l = a.w - r0;  if ((unsigned)l < H2_BINS) atomicAdd(&bins32[l >> 1], 1u << ((l & 1) << 4));
        l = bb.x - r0; if ((unsigned)l < H2_BINS) atomicAdd(&bins32[l >> 1], 1u << ((l & 1) << 4));
        l = bb.y - r0; if ((unsigned)l < H2_BINS) atomicAdd(&bins32[l >> 1], 1u << ((l & 1) << 4));
        l = bb.z - r0; if ((unsigned)l < H2_BINS) atomicAdd(&bins32[l >> 1], 1u << ((l & 1) << 4));
        l = bb.w - r0; if ((unsigned)l < H2_BINS) atomicAdd(&bins32[l >> 1], 1u << ((l & 1) << 4));
    }
    __syncthreads();
    int bound = min(H2_BINS, N_NODES - r0);    // 32768 or 17232 (both even)
    int* dst = (type == 0 ? pcnt_out : pcnt_in) + (size_t)c * NROWS_ALL + p * N_NODES + r0;
    for (int j = tid; j < bound / 2; j += 256) {
        unsigned u = bins32[j];
        int2 w = make_int2((int)(u & 0xFFFFu), (int)(u >> 16));
        *(int2*)(dst + 2 * j) = w;
    }
}

// ---------------- scan pass1 (fused merge): chunk-private sums -> cnt/sc_out, block sums ----------------
__global__ __launch_bounds__(256) void scan_pass1(const int* __restrict__ pcnt_out,
                                                  const int* __restrict__ pcnt_in,
                                                  int* __restrict__ cnt_out,
                                                  int* __restrict__ cnt_in,
                                                  float* __restrict__ sc_out,
                                                  int* __restrict__ partial) {
    __shared__ int lds[256];
    int t = threadIdx.x;
    int base = blockIdx.x * 1024 + t * 4;
    int4 ci = make_int4(0, 0, 0, 0);
    if (base < NROWS_ALL) {
        int4 co = make_int4(0, 0, 0, 0);
#pragma unroll
        for (int c = 0; c < HB_CHUNKS; ++c) {
            int4 vi = *(const int4*)(pcnt_in + (size_t)c * NROWS_ALL + base);
            int4 vo = *(const int4*)(pcnt_out + (size_t)c * NROWS_ALL + base);
            ci.x += vi.x; ci.y += vi.y; ci.z += vi.z; ci.w += vi.w;
            co.x += vo.x; co.y += vo.y; co.z += vo.z; co.w += vo.w;
        }
        *(int4*)(cnt_in + base) = ci;
        *(int4*)(cnt_out + base) = co;
        float4 sc;
        sc.x = rsqrtf(fmaxf((float)co.x, 1.0f));
        sc.y = rsqrtf(fmaxf((float)co.y, 1.0f));
        sc.z = rsqrtf(fmaxf((float)co.z, 1.0f));
        sc.w = rsqrtf(fmaxf((float)co.w, 1.0f));
        *(float4*)(sc_out + base) = sc;
    }
    int s = ci.x + ci.y + ci.z + ci.w;
    lds[t] = s; __syncthreads();
    for (int off = 1; off < 256; off <<= 1) {
        int u = (t >= off) ? lds[t - off] : 0;
        __syncthreads();
        lds[t] += u;
        __syncthreads();
    }
    if (t == 255) partial[blockIdx.x] = lds[255];
}

__global__ __launch_bounds__(256) void scan_pass2(int* __restrict__ partial) {
    __shared__ int lds[256];
    int t = threadIdx.x;
    int s = (t < SCAN_BLOCKS) ? partial[t] : 0;
    lds[t] = s; __syncthreads();
    for (int off = 1; off < 256; off <<= 1) {
        int u = (t >= off) ? lds[t - off] : 0;
        __syncthreads();
        lds[t] += u;
        __syncthreads();
    }
    if (t < SCAN_BLOCKS) partial[t] = lds[t] - s;
}

// ---------------- scan pass3 (fused chunkbase): cursor + per-chunk write bases ----------------
__global__ __launch_bounds__(256) void scan_pass3(const int* __restrict__ cnt,
                                                  const int* __restrict__ partial,
                                                  int* __restrict__ cursor,
                                                  int* __restrict__ pcnt_in) {
    __shared__ int lds[256];
    int t = threadIdx.x;
    int base = blockIdx.x * 1024 + t * 4;
    int4 v = make_int4(0, 0, 0, 0);
    if (base < NROWS_ALL) v = *(const int4*)(cnt + base);
    int s = v.x + v.y + v.z + v.w;
    lds[t] = s; __syncthreads();
    for (int off = 1; off < 256; off <<= 1) {
        int u = (t >= off) ? lds[t - off] : 0;
        __syncthreads();
        lds[t] += u;
        __syncthreads();
    }
    if (base < NROWS_ALL) {
        int run = partial[blockIdx.x] + lds[t] - s;
        int vv[4] = {v.x, v.y, v.z, v.w};
        int rb[4];
#pragma unroll
        for (int j = 0; j < 4; ++j) { cursor[base + j] = run; rb[j] = run; run += vv[j]; }
#pragma unroll
        for (int c = 0; c < HB_CHUNKS; ++c) {
            int4 pc = *(const int4*)(pcnt_in + (size_t)c * NROWS_ALL + base);
            *(int4*)(pcnt_in + (size_t)c * NROWS_ALL + base) = make_int4(rb[0], rb[1], rb[2], rb[3]);
            rb[0] += pc.x; rb[1] += pc.y; rb[2] += pc.z; rb[3] += pc.w;
        }
    }
}

// ---------------- fill2: place (src | f16(sc)<<16) via LDS cursors ----------------
__global__ __launch_bounds__(256) void fill2_kernel(const int* __restrict__ esrc,
                                                    const int* __restrict__ edst,
                                                    const int* __restrict__ pcnt_in,
                                                    const float* __restrict__ sc_out,
                                                    unsigned int* __restrict__ colsc) {
    __shared__ int curs[HF_BINS];
    int tid = threadIdx.x;
    int b = blockIdx.x;
    int c = b % HB_CHUNKS;
    int r = (b / HB_CHUNKS) % HF_RANGES;
    int p = b / (HB_CHUNKS * HF_RANGES);
    int r0 = r * HF_BINS;
    int bound = min(HF_BINS, N_NODES - r0);
    const int* basep = pcnt_in + (size_t)c * NROWS_ALL + p * N_NODES + r0;
    for (int i = tid; i < bound; i += 256) curs[i] = basep[i];
    __syncthreads();
    const float* scp = sc_out + p * N_NODES;
    const int4* sp4 = (const int4*)(esrc + (size_t)p * N_EDGES + c * CHUNK_E);
    const int4* dp4 = (const int4*)(edst + (size_t)p * N_EDGES + c * CHUNK_E);
    for (int i = tid * 2; i < CHUNK_E / 4; i += 512) {
        int4 dv0 = dp4[i];
        int4 dv1 = dp4[i + 1];
        int4 sv0 = sp4[i];
        int4 sv1 = sp4[i + 1];
        int l;
        l = dv0.x - r0; if ((unsigned)l < HF_BINS) { int pos = atomicAdd(&curs[l], 1); colsc[pos] = (unsigned)sv0.x | ((unsigned)__half_as_ushort(__float2half(scp[sv0.x])) << 16); }
        l = dv0.y - r0; if ((unsigned)l < HF_BINS) { int pos = atomicAdd(&curs[l], 1); colsc[pos] = (unsigned)sv0.y | ((unsigned)__half_as_ushort(__float2half(scp[sv0.y])) << 16); }
        l = dv0.z - r0; if ((unsigned)l < HF_BINS) { int pos = atomicAdd(&curs[l], 1); colsc[pos] = (unsigned)sv0.z | ((unsigned)__half_as_ushort(__float2half(scp[sv0.z])) << 16); }
        l = dv0.w - r0; if ((unsigned)l < HF_BINS) { int pos = atomicAdd(&curs[l], 1); colsc[pos] = (unsigned)sv0.w | ((unsigned)__half_as_ushort(__float2half(scp[sv0.w])) << 16); }
        l = dv1.x - r0; if ((unsigned)l < HF_BINS) { int pos = atomicAdd(&curs[l], 1); colsc[pos] = (unsigned)sv1.x | ((unsigned)__half_as_ushort(__float2half(scp[sv1.x])) << 16); }
        l = dv1.y - r0; if ((unsigned)l < HF_BINS) { int pos = atomicAdd(&curs[l], 1); colsc[pos] = (unsigned)sv1.y | ((unsigned)__half_as_ushort(__float2half(scp[sv1.y])) << 16); }
        l = dv1.z - r0; if ((unsigned)l < HF_BINS) { int pos = atomicAdd(&curs[l], 1); colsc[pos] = (unsigned)sv1.z | ((unsigned)__half_as_ushort(__float2half(scp[sv1.z])) << 16); }
        l = dv1.w - r0; if ((unsigned)l < HF_BINS) { int pos = atomicAdd(&curs[l], 1); colsc[pos] = (unsigned)sv1.w | ((unsigned)__half_as_ushort(__float2half(scp[sv1.w])) << 16); }
    }
}

// ---------------- gather: 4 edge-slots x 16 lanes (full 256B row), colsc packed, unrolled x2 ----------------
__global__ __launch_bounds__(256) void gather_kernel(const int* __restrict__ cursor,
                                                     const int* __restrict__ cnt_in,
                                                     const unsigned int* __restrict__ colsc,
                                                     const uint4* __restrict__ hb4,
                                                     uint4* __restrict__ aggb4) {
    int wid = blockIdx.x * 4 + (threadIdx.x >> 6);
    int lane = threadIdx.x & 63;
    int ss = lane >> 4;          // edge slot 0..3
    int ln = lane & 15;          // dim group: full row, 16 uint4
    if (wid >= NROWS_ALL) return;
    int beg = cursor[wid];
    int end = beg + cnt_in[wid];
    float acc[8] = {};
    int e = beg + ss;
    for (; e + 4 < end; e += 8) {
        unsigned cs0 = colsc[e];
        unsigned cs1 = colsc[e + 4];
        int s0 = cs0 & 0xFFFF;
        int s1 = cs1 & 0xFFFF;
        float c0 = __half2float(__ushort_as_half((unsigned short)(cs0 >> 16)));
        float c1 = __half2float(__ushort_as_half((unsigned short)(cs1 >> 16)));
        uint4 v0 = hb4[s0 * 16 + ln];
        uint4 v1 = hb4[s1 * 16 + ln];
        acc[0] = fmaf(__uint_as_float(v0.x << 16),        c0, acc[0]);
        acc[1] = fmaf(__uint_as_float(v0.x & 0xFFFF0000u), c0, acc[1]);
        acc[2] = fmaf(__uint_as_float(v0.y << 16),        c0, acc[2]);
        acc[3] = fmaf(__uint_as_float(v0.y & 0xFFFF0000u), c0, acc[3]);
        acc[4] = fmaf(__uint_as_float(v0.z << 16),        c0, acc[4]);
        acc[5] = fmaf(__uint_as_float(v0.z & 0xFFFF0000u), c0, acc[5]);
        acc[6] = fmaf(__uint_as_float(v0.w << 16),        c0, acc[6]);
        acc[7] = fmaf(__uint_as_float(v0.w & 0xFFFF0000u), c0, acc[7]);
        acc[0] = fmaf(__uint_as_float(v1.x << 16),        c1, acc[0]);
        acc[1] = fmaf(__uint_as_float(v1.x & 0xFFFF0000u), c1, acc[1]);
        acc[2] = fmaf(__uint_as_float(v1.y << 16),        c1, acc[2]);
        acc[3] = fmaf(__uint_as_float(v1.y & 0xFFFF0000u), c1, acc[3]);
        acc[4] = fmaf(__uint_as_float(v1.z << 16),        c1, acc[4]);
        acc[5] = fmaf(__uint_as_float(v1.z & 0xFFFF0000u), c1, acc[5]);
        acc[6] = fmaf(__uint_as_float(v1.w << 16),        c1, acc[6]);
        acc[7] = fmaf(__uint_as_float(v1.w & 0xFFFF0000u), c1, acc[7]);
    }
    if (e < end) {
        unsigned cs0 = colsc[e];
        int s0 = cs0 & 0xFFFF;
        float c0 = __half2float(__ushort_as_half((unsigned short)(cs0 >> 16)));
        uint4 v0 = hb4[s0 * 16 + ln];
        acc[0] = fmaf(__uint_as_float(v0.x << 16),        c0, acc[0]);
        acc[1] = fmaf(__uint_as_float(v0.x & 0xFFFF0000u), c0, acc[1]);
        acc[2] = fmaf(__uint_as_float(v0.y << 16),        c0, acc[2]);
        acc[3] = fmaf(__uint_as_float(v0.y & 0xFFFF0000u), c0, acc[3]);
        acc[4] = fmaf(__uint_as_float(v0.z << 16),        c0, acc[4]);
        acc[5] = fmaf(__uint_as_float(v0.z & 0xFFFF0000u), c0, acc[5]);
        acc[6] = fmaf(__uint_as_float(v0.w << 16),        c0, acc[6]);
        acc[7] = fmaf(__uint_as_float(v0.w & 0xFFFF0000u), c0, acc[7]);
    }
#pragma unroll
    for (int j = 0; j < 8; ++j) {
        acc[j] += __shfl_xor(acc[j], 16, 64);
        acc[j] += __shfl_xor(acc[j], 32, 64);
    }
    if (ss == 0) {
        uint4 o;
        o.x = f2bf(acc[0]) | ((unsigned)f2bf(acc[1]) << 16);
        o.y = f2bf(acc[2]) | ((unsigned)f2bf(acc[3]) << 16);
        o.z = f2bf(acc[4]) | ((unsigned)f2bf(acc[5]) << 16);
        o.w = f2bf(acc[6]) | ((unsigned)f2bf(acc[7]) << 16);
        int t = wid >> 4, m = wid & 15, q = ln >> 2, qd = ln & 3;
        aggb4[(size_t)t * 256 + q * 64 + qd * 16 + m] = o;
    }
}

// ---------------- score pass: gemm1 -> LDS transpose -> gemm2 -> tanh -> score ----------------
__global__ __launch_bounds__(256, 4) void score_pass(const uint4* __restrict__ aggb4,
                                                     const uint4* __restrict__ wsw,
                                                     const int* __restrict__ cnt_in,
                                                     const float* __restrict__ b_gc,
                                                     const float* __restrict__ b1,
                                                     const float* __restrict__ w2,
                                                     float* __restrict__ scorep) {
    __shared__ float zS[4][16][132];
    int wave = threadIdx.x >> 6, lane = threadIdx.x & 63;
    int m = lane & 15, quad = lane >> 4;
    int t = blockIdx.x * 4 + wave;
    if (t >= NTILES_ALL) return;
    int r0 = t * 16;
    int p = r0 / N_NODES;
    const uint4* At = aggb4 + (size_t)t * 256 + lane;
    bf16x8 a[4];
#pragma unroll
    for (int q = 0; q < 4; ++q) a[q] = *(const bf16x8*)&At[q * 64];
    float s[4];
#pragma unroll
    for (int rg = 0; rg < 4; ++rg)
        s[rg] = rsqrtf(fmaxf((float)cnt_in[r0 + quad * 4 + rg], 1.0f));
    const uint4* Bp = wsw + (size_t)p * 2048 + lane;
    const float* bgc = b_gc + p * DIM;
    float (*zw)[132] = zS[wave];
#pragma unroll
    for (int n0 = 0; n0 < 8; ++n0) {
        f32x4 acc = {0.f, 0.f, 0.f, 0.f};
#pragma unroll
        for (int q = 0; q < 4; ++q) {
            bf16x8 b = *(const bf16x8*)&Bp[(n0 * 4 + q) * 64];
            acc = __builtin_amdgcn_mfma_f32_16x16x32_bf16(a[q], b, acc, 0, 0, 0);
        }
        int colj = n0 * 16 + m;
        float bias = bgc[colj];
#pragma unroll
        for (int rg = 0; rg < 4; ++rg)
            zw[quad * 4 + rg][colj] = acc[rg] * s[rg] + bias;
    }
    bf16x8 sa[4];
#pragma unroll
    for (int q = 0; q < 4; ++q) {
        const float* pr = &zw[m][q * 32 + quad * 8];
        float4 f0 = *(const float4*)pr;
        float4 f1 = *(const float4*)(pr + 4);
        bf16x8 tt;
        tt[0] = f2bf(f0.x); tt[1] = f2bf(f0.y); tt[2] = f2bf(f0.z); tt[3] = f2bf(f0.w);
        tt[4] = f2bf(f1.x); tt[5] = f2bf(f1.y); tt[6] = f2bf(f1.z); tt[7] = f2bf(f1.w);
        sa[q] = tt;
    }
    const uint4* W1 = wsw + (size_t)N_PATHS * 2048 + lane;
    float rsum[4] = {0.f, 0.f, 0.f, 0.f};
#pragma unroll
    for (int n0 = 0; n0 < 8; ++n0) {
        f32x4 acc = {0.f, 0.f, 0.f, 0.f};
#pragma unroll
        for (int q = 0; q < 4; ++q) {
            bf16x8 b = *(const bf16x8*)&W1[(n0 * 4 + q) * 64];
            acc = __builtin_amdgcn_mfma_f32_16x16x32_bf16(sa[q], b, acc, 0, 0, 0);
        }
        int colj = n0 * 16 + m;
        float bj = b1[colj], wj = w2[colj];
#pragma unroll
        for (int rg = 0; rg < 4; ++rg)
            rsum[rg] += tanh_fast(acc[rg] + bj) * wj;
    }
#pragma unroll
    for (int off = 1; off < 64; off <<= 1)
#pragma unroll
        for (int rg = 0; rg < 4; ++rg) rsum[rg] += __shfl_xor(rsum[rg], off, 64);
    if (lane == 0)
        scorep[t] = rsum[0] + rsum[1] + rsum[2] + rsum[3];
}

// ---------------- beta = softmax( path-bucketed mean of scorep ) ----------------
__global__ __launch_bounds__(1024) void beta_kernel(const float* __restrict__ scorep,
                                                    float* __restrict__ beta) {
    __shared__ float red[3][1024];
    int t = threadIdx.x;
    float a0 = 0.f, a1 = 0.f, a2 = 0.f;
    for (int i = t; i < NTILES_ALL; i += 1024) {
        float v = scorep[i];
        int p = (i * 16) / N_NODES;
        if (p == 0) a0 += v; else if (p == 1) a1 += v; else a2 += v;
    }
    red[0][t] = a0; red[1][t] = a1; red[2][t] = a2;
    __syncthreads();
    for (int off = 512; off > 0; off >>= 1) {
        if (t < off) {
            red[0][t] += red[0][t + off];
            red[1][t] += red[1][t + off];
            red[2][t] += red[2][t + off];
        }
        __syncthreads();
    }
    if (t == 0) {
        float a = red[0][0] / (float)N_NODES;
        float b = red[1][0] / (float)N_NODES;
        float c = red[2][0] / (float)N_NODES;
        float mx = fmaxf(a, fmaxf(b, c));
        float e0 = expf(a - mx), e1 = expf(b - mx), e2 = expf(c - mx);
        float sm = e0 + e1 + e2;
        beta[0] = e0 / sm; beta[1] = e1 / sm; beta[2] = e2 / sm;
    }
}

// ---------------- out pass: out = sum_p beta_p * ((agg_p @ W_p)*s + b_p) ----------------
__global__ __launch_bounds__(256, 4) void out_pass(const uint4* __restrict__ aggb4,
                                                   const uint4* __restrict__ wsw,
                                                   const int* __restrict__ cnt_in,
                                                   const float* __restrict__ b_gc,
                                                   const float* __restrict__ beta,
                                                   float* __restrict__ out) {
    __shared__ float zS[4][16][132];
    int wave = threadIdx.x >> 6, lane = threadIdx.x & 63;
    int m = lane & 15, quad = lane >> 4;
    int t = blockIdx.x * 4 + wave;
    if (t >= NTILES_N) return;
    int r0 = t * 16;
    float of[8][4] = {};
#pragma unroll
    for (int p = 0; p < N_PATHS; ++p) {
        const uint4* At = aggb4 + (size_t)(p * NTILES_N + t) * 256 + lane;
        bf16x8 a[4];
#pragma unroll
        for (int q = 0; q < 4; ++q) a[q] = *(const bf16x8*)&At[q * 64];
        float s[4];
#pragma unroll
        for (int rg = 0; rg < 4; ++rg)
            s[rg] = rsqrtf(fmaxf((float)cnt_in[p * N_NODES + r0 + quad * 4 + rg], 1.0f));
        float bp = beta[p];
        const uint4* Bp = wsw + (size_t)p * 2048 + lane;
        const float* bgc = b_gc + p * DIM;
#pragma unroll
        for (int n0 = 0; n0 < 8; ++n0) {
            f32x4 acc = {0.f, 0.f, 0.f, 0.f};
#pragma unroll
            for (int q = 0; q < 4; ++q) {
                bf16x8 b = *(const bf16x8*)&Bp[(n0 * 4 + q) * 64];
                acc = __builtin_amdgcn_mfma_f32_16x16x32_bf16(a[q], b, acc, 0, 0, 0);
            }
            float bias = bgc[n0 * 16 + m];
#pragma unroll
            for (int rg = 0; rg < 4; ++rg)
                of[n0][rg] = fmaf(bp, acc[rg] * s[rg] + bias, of[n0][rg]);
        }
    }
    float (*zw)[132] = zS[wave];
#pragma unroll
    for (int n0 = 0; n0 < 8; ++n0)
#pragma unroll
        for (int rg = 0; rg < 4; ++rg)
            zw[quad * 4 + rg][n0 * 16 + m] = of[n0][rg];
#pragma unroll
    for (int i = 0; i < 8; ++i) {
        int fi = i * 64 + lane;
        int row = fi >> 5, c4 = fi & 31;
        float4 v = *(const float4*)&zw[row][c4 * 4];
        *(float4*)(out + (size_t)(r0 + row) * DIM + c4 * 4) = v;
    }
}

extern "C" void kernel_launch(void* const* d_in, const int* in_sizes, int n_in,
                              void* d_out, int out_size, void* d_ws, size_t ws_size,
                              hipStream_t stream) {
    const float* h    = (const float*)d_in[0];
    const float* W_gc = (const float*)d_in[1];
    const float* b_gc = (const float*)d_in[2];
    const float* w1   = (const float*)d_in[3];
    const float* b1   = (const float*)d_in[4];
    const float* w2   = (const float*)d_in[5];
    const int* esrc   = (const int*)d_in[6];
    const int* edst   = (const int*)d_in[7];
    float* out        = (float*)d_out;

    // workspace layout (4-byte word offsets)
    int*   cnt_out = (int*)d_ws;                                // 150000
    int*   cnt_in  = cnt_out + NROWS_ALL;                       // 150000
    float* beta    = (float*)d_ws + 300004;                     // 4 (+pad)
    int*   partial = (int*)d_ws + 300032;                       // 256
    float* sc_out  = (float*)d_ws + 300288;                     // 150000 (reused as scorep)
    float* scorep  = (float*)d_ws + 300288;                     //   after gather completes
    uint4* wsw     = (uint4*)((int*)d_ws + 450288);             // 32768 words
    unsigned int* aggb = (unsigned int*)((int*)d_ws + 483056);  // 9.6M words
    int*   cursor  = (int*)d_ws + 10233056;                     // 150000
    unsigned int* colsc = (unsigned int*)((int*)d_ws + 10383056);    // 1.8M words
    unsigned int* hb    = (unsigned int*)((int*)d_ws + 12183056);    // 3.2M words
    int*   pcnt_out = (int*)d_ws + 15383056;                    // 3.6M words
    int*   pcnt_in  = (int*)d_ws + 18983056;                    // 3.6M words (ends 22.58M)

    conv_h<<<(N_NODES * DIM / 8 + 255) / 256, 256, 0, stream>>>(h, hb);
    conv_w<<<((N_PATHS + 1) * 2048 + 255) / 256, 256, 0, stream>>>(W_gc, w1, wsw);

    hist_kernel<<<2 * N_PATHS * H2_RANGES * HB_CHUNKS, 256, 0, stream>>>(
        esrc, edst, pcnt_out, pcnt_in);

    scan_pass1<<<SCAN_BLOCKS, 256, 0, stream>>>(
        pcnt_out, pcnt_in, cnt_out, cnt_in, sc_out, partial);
    scan_pass2<<<1, 256, 0, stream>>>(partial);
    scan_pass3<<<SCAN_BLOCKS, 256, 0, stream>>>(cnt_in, partial, cursor, pcnt_in);

    fill2_kernel<<<N_PATHS * HF_RANGES * HB_CHUNKS, 256, 0, stream>>>(
        esrc, edst, pcnt_in, sc_out, colsc);

    gather_kernel<<<(NROWS_ALL + 3) / 4, 256, 0, stream>>>(
        cursor, cnt_in, colsc, (const uint4*)hb, (uint4*)aggb);

    score_pass<<<(NTILES_ALL + 3) / 4, 256, 0, stream>>>(
        (const uint4*)aggb, wsw, cnt_in, b_gc, b1, w2, scorep);

    beta_kernel<<<1, 1024, 0, stream>>>(scorep, beta);

    out_pass<<<(NTILES_N + 3) / 4, 256, 0, stream>>>(
        (const uint4*)aggb, wsw, cnt_in, b_gc, beta, out);
}